// Round 11
// baseline (189.326 us; speedup 1.0000x reference)
//
#include <hip/hip_runtime.h>
#include <hip/hip_bf16.h>

#define S 4096
#define D 256
#define NB 4

typedef __attribute__((ext_vector_type(8))) __bf16 bf16x8;
typedef __attribute__((ext_vector_type(8))) short s16x8;
typedef __attribute__((ext_vector_type(4))) short s16x4;
typedef __attribute__((ext_vector_type(4))) float f32x4;
typedef __attribute__((ext_vector_type(8))) _Float16 h16x8;

#define MFMA(a, b, c) __builtin_amdgcn_mfma_f32_16x16x32_bf16(a, b, c, 0, 0, 0)
#define MFMA8(a, b, c) __builtin_amdgcn_mfma_f32_16x16x32_fp8_fp8(a, b, c, 0, 0, 0)

__device__ __forceinline__ short f2bf(float f) {
    union { float f; unsigned u; } v; v.f = f;
    unsigned r = v.u + 0x7fffu + ((v.u >> 16) & 1u);   // RNE
    return (short)(r >> 16);
}

__device__ __forceinline__ void g2lds16(const char* g, char* l) {
    __builtin_amdgcn_global_load_lds(
        (const __attribute__((address_space(1))) unsigned int*)g,
        (__attribute__((address_space(3))) unsigned int*)l, 16, 0, 0);
}

// ---------------- prep: x -> fp8(XOR-swizzled) + bf16 x^T + row norms; W -> bf16 ----------------
// 512 threads, 64 s-rows per block. Vectorized transpose (ds_read_b64 + register 4x8
// transpose + 16B global writes). Deterministic; first-launch-verified in R10.
__global__ __launch_bounds__(512) void k_prep(const float* __restrict__ x,
                                              const float* __restrict__ Wv,
                                              unsigned char* __restrict__ xb8,
                                              short* __restrict__ xt,
                                              short* __restrict__ wb,
                                              float* __restrict__ sqg) {
    const int tid = threadIdx.x;
    if (blockIdx.x >= 256) {   // W fp32 -> bf16 (8 blocks x 512 threads x 16 elems)
        int idx = (((int)blockIdx.x - 256) * 512 + tid) * 16;
        #pragma unroll
        for (int h = 0; h < 2; h++) {
            float4 f0 = *(const float4*)(Wv + idx + h * 8);
            float4 f1 = *(const float4*)(Wv + idx + h * 8 + 4);
            s16x8 o;
            o[0] = f2bf(f0.x); o[1] = f2bf(f0.y); o[2] = f2bf(f0.z); o[3] = f2bf(f0.w);
            o[4] = f2bf(f1.x); o[5] = f2bf(f1.y); o[6] = f2bf(f1.z); o[7] = f2bf(f1.w);
            *(s16x8*)(wb + idx + h * 8) = o;
        }
        return;
    }

    __shared__ short sX[64 * 264];
    const int b = blockIdx.x >> 6, s0 = (blockIdx.x & 63) * 64;
    {
        const int row = tid >> 3, c8 = tid & 7;
        const float* src = x + (size_t)(b * S + s0 + row) * D + c8 * 32;
        unsigned char* xrow = xb8 + (size_t)(b * S + s0 + row) * D;
        float ss = 0.f;
        int p8[8];
        #pragma unroll
        for (int j = 0; j < 8; j++) {
            float4 v = ((const float4*)src)[j];
            ss += v.x * v.x + v.y * v.y + v.z * v.z + v.w * v.w;
            s16x4 o;
            o.x = f2bf(v.x); o.y = f2bf(v.y); o.z = f2bf(v.z); o.w = f2bf(v.w);
            *(s16x4*)(sX + row * 264 + c8 * 32 + j * 4) = o;
            int pk = __builtin_amdgcn_cvt_pk_fp8_f32(v.x, v.y, 0, false);
            p8[j] = __builtin_amdgcn_cvt_pk_fp8_f32(v.z, v.w, pk, true);
        }
        ss += __shfl_xor(ss, 1, 64);
        ss += __shfl_xor(ss, 2, 64);
        ss += __shfl_xor(ss, 4, 64);
        int4 lo = {p8[0], p8[1], p8[2], p8[3]};
        int4 hi = {p8[4], p8[5], p8[6], p8[7]};
        *(int4*)(xrow + (((2 * c8) ^ (row & 7)) << 4)) = lo;
        *(int4*)(xrow + (((2 * c8 + 1) ^ (row & 7)) << 4)) = hi;
        if (c8 == 0) sqg[b * S + s0 + row] = ss;
    }
    __syncthreads();
    {   // transpose-out: thread owns 4 d-cols x 8 s-rows
        const int d4 = (tid & 63) * 4, sg = (tid >> 6) * 8;
        s16x4 sh[8];
        #pragma unroll
        for (int j = 0; j < 8; j++)
            sh[j] = *(const s16x4*)(sX + (sg + j) * 264 + d4);
        #pragma unroll
        for (int k = 0; k < 4; k++) {
            s16x8 o;
            #pragma unroll
            for (int j = 0; j < 8; j++) o[j] = sh[j][k];
            *(s16x8*)(xt + (size_t)(b * D + d4 + k) * S + s0 + sg) = o;
        }
    }
}

// ---------------- Main fused attention (R9 body, t-tile 32; launch_bounds(256,3)) ----------------
// 256 threads = 4 waves. q-tile 64, t-tile 32. Gram fp8 (A=regs, B=LDS), PV bf16 vs x^T.
// Writes UNNORMALIZED Y = K@x (fp16) + rowsums; k_post normalizes and applies W^T+b.
// (256,3): unified regs 156 <= 168 cap -> no spill; invites 3 blocks/CU if HW granule allows.
template <int TSPLIT>
__global__ __launch_bounds__(256, 3) void k_attn(const unsigned char* __restrict__ xb8,
                                                 const short* __restrict__ xt,
                                                 const float* __restrict__ sq,
                                                 const float* __restrict__ logt,
                                                 _Float16* __restrict__ pex,
                                                 float* __restrict__ rws) {
    __shared__ char sXt[2][32 * 256];
    __shared__ short sK[2][64 * 36];
    __shared__ float sRow[64];

    const int tid = threadIdx.x;
    const int w = tid >> 6, lane = tid & 63;
    const int col = lane & 15, quad = lane >> 4;
    const int cx = col & 7;

    const int b  = (blockIdx.x & 7) >> 1;
    const int th = blockIdx.x & 1;
    const int qt = blockIdx.x >> 3;
    const int q0 = qt * 64;
    const int t_base = th * (S / TSPLIT);
    const int NT = (S / TSPLIT) / 32;

    float temp = fmaxf(__expf(logt[0]), 1e-5f);
    float t2 = temp * temp;
    float t2inv = __builtin_amdgcn_rcpf(t2);

    const unsigned char* xtb = xb8 + (size_t)b * S * D;
    const short* vtb = xt + (size_t)b * D * S;
    const float* sqb = sq + b * S;

    long xq[8];
    {
        const unsigned char* xrow = xtb + (size_t)(q0 + w * 16 + col) * D;
        #pragma unroll
        for (int ks = 0; ks < 8; ks++)
            xq[ks] = *(const long*)(xrow + (((ks * 2 + (quad >> 1)) ^ cx) << 4) + (quad & 1) * 8);
    }
    float sqq[4];
    #pragma unroll
    for (int rr = 0; rr < 4; rr++)
        sqq[rr] = sqb[q0 + w * 16 + quad * 4 + rr];

    f32x4 acc[4][4];
    #pragma unroll
    for (int mi = 0; mi < 4; mi++)
        #pragma unroll
        for (int ni = 0; ni < 4; ni++)
            acc[mi][ni] = (f32x4){0.f, 0.f, 0.f, 0.f};
    float rs[4] = {0.f, 0.f, 0.f, 0.f};

    {   // prologue: async-stage tile 0
        const char* g = (const char*)(xtb + (size_t)t_base * D);
        #pragma unroll
        for (int p = 0; p < 2; p++) {
            int c = p * 256 + tid;
            g2lds16(g + c * 16, &sXt[0][c * 16]);
        }
    }

    for (int i = 0; i < NT; i++) {
        const int t0 = t_base + i * 32;
        const int cur = i & 1;
        __syncthreads();

        if (i + 1 < NT) {
            const char* g = (const char*)(xtb + (size_t)(t0 + 32) * D);
            #pragma unroll
            for (int p = 0; p < 2; p++) {
                int c = p * 256 + tid;
                g2lds16(g + c * 16, &sXt[cur ^ 1][c * 16]);
            }
        }

        bf16x8 vb[4];
        if (i > 0) {
            const int tp = t0 - 32;
            #pragma unroll
            for (int ni = 0; ni < 4; ni++)
                vb[ni] = *(const bf16x8*)(vtb + (size_t)(w * 64 + ni * 16 + col) * S + tp + quad * 8);
        }
        float sqt0 = sqb[t0 + col], sqt1 = sqb[t0 + 16 + col];

        f32x4 p2v[2];
        p2v[0] = (f32x4){0.f, 0.f, 0.f, 0.f};
        p2v[1] = (f32x4){0.f, 0.f, 0.f, 0.f};
        #pragma unroll
        for (int ks = 0; ks < 8; ks++) {
            int co = (((ks * 2 + (quad >> 1)) ^ cx) << 4) + (quad & 1) * 8;
            long b0 = *(const long*)(&sXt[cur][col * 256 + co]);
            long b1 = *(const long*)(&sXt[cur][(col + 16) * 256 + co]);
            p2v[0] = MFMA8(xq[ks], b0, p2v[0]);
            p2v[1] = MFMA8(xq[ks], b1, p2v[1]);
        }

        #pragma unroll
        for (int t_ = 0; t_ < 2; t_++) {
            float sqt = t_ ? sqt1 : sqt0;
            int tg = t0 + t_ * 16 + col;
            #pragma unroll
            for (int rr = 0; rr < 4; rr++) {
                float d2 = fmaxf(sqq[rr] + sqt - 2.f * p2v[t_][rr], 0.f);
                float u = __builtin_amdgcn_rcpf(t2 + d2);   // normalization cancels t2
                if (q0 + w * 16 + quad * 4 + rr == tg) u = t2inv;   // exact diagonal (kv=1)
                rs[rr] += u;
                sK[cur][(w * 16 + quad * 4 + rr) * 36 + t_ * 16 + col] = f2bf(u);
            }
        }

        if (i > 0) {
            #pragma unroll
            for (int mi = 0; mi < 4; mi++) {
                bf16x8 af = *(const bf16x8*)(&sK[cur ^ 1][(mi * 16 + col) * 36 + quad * 8]);
                #pragma unroll
                for (int ni = 0; ni < 4; ni++)
                    acc[mi][ni] = MFMA(af, vb[ni], acc[mi][ni]);
            }
        }
    }

    __syncthreads();
    {   // final PV
        const int tp = t_base + (NT - 1) * 32;
        const int cur = (NT - 1) & 1;
        bf16x8 vb[4];
        #pragma unroll
        for (int ni = 0; ni < 4; ni++)
            vb[ni] = *(const bf16x8*)(vtb + (size_t)(w * 64 + ni * 16 + col) * S + tp + quad * 8);
        #pragma unroll
        for (int mi = 0; mi < 4; mi++) {
            bf16x8 af = *(const bf16x8*)(&sK[cur][(mi * 16 + col) * 36 + quad * 8]);
            #pragma unroll
            for (int ni = 0; ni < 4; ni++)
                acc[mi][ni] = MFMA(af, vb[ni], acc[mi][ni]);
        }
    }

    #pragma unroll
    for (int rr = 0; rr < 4; rr++) {
        float v = rs[rr];
        v += __shfl_xor(v, 1, 64);
        v += __shfl_xor(v, 2, 64);
        v += __shfl_xor(v, 4, 64);
        v += __shfl_xor(v, 8, 64);
        if (col == 0) sRow[w * 16 + quad * 4 + rr] = v;
    }
    __syncthreads();

    if (tid < 64) rws[(size_t)th * NB * S + b * S + q0 + tid] = sRow[tid];
    _Float16* ob = pex + (size_t)th * NB * S * D + (size_t)(b * S + q0) * D;
    #pragma unroll
    for (int mi = 0; mi < 4; mi++)
        #pragma unroll
        for (int rr = 0; rr < 4; rr++)
            #pragma unroll
            for (int ni = 0; ni < 4; ni++)
                ob[(size_t)(mi * 16 + quad * 4 + rr) * D + w * 64 + ni * 16 + col] =
                    (_Float16)acc[mi][ni][rr];
}

// ---------------- post: out = ((Y0+Y1)/(r0+r1)) @ W^T + b ----------------
__global__ __launch_bounds__(256) void k_post(const _Float16* __restrict__ pex,
                                              const float* __restrict__ rws,
                                              const short* __restrict__ wb,
                                              const float* __restrict__ bv,
                                              float* __restrict__ out) {
    __shared__ short sY[32 * 264];

    const int tid = threadIdx.x;
    const int w = tid >> 6, lane = tid & 63;
    const int col = lane & 15, quad = lane >> 4;
    const int b = blockIdx.x >> 7, s0 = (blockIdx.x & 127) * 32;

    bf16x8 wf[4][8];
    #pragma unroll
    for (int ni = 0; ni < 4; ni++)
        #pragma unroll
        for (int ks = 0; ks < 8; ks++)
            wf[ni][ks] = *(const bf16x8*)(wb + (size_t)(w * 64 + ni * 16 + col) * D + ks * 32 + quad * 8);

    {   // load partials, normalize, stage bf16
        const int row = tid >> 3, c8 = tid & 7;
        const int gs = b * S + s0 + row;
        float rinv = __builtin_amdgcn_rcpf(fmaxf(rws[gs] + rws[(size_t)NB * S + gs], 1e-8f));
        const _Float16* y0 = pex + (size_t)gs * D + c8 * 32;
        const _Float16* y1 = y0 + (size_t)NB * S * D;
        #pragma unroll
        for (int j = 0; j < 4; j++) {
            h16x8 a = *(const h16x8*)(y0 + j * 8);
            h16x8 c = *(const h16x8*)(y1 + j * 8);
            s16x8 o;
            #pragma unroll
            for (int e = 0; e < 8; e++)
                o[e] = f2bf(((float)a[e] + (float)c[e]) * rinv);
            *(s16x8*)(sY + row * 264 + c8 * 32 + j * 8) = o;
        }
    }
    __syncthreads();

    f32x4 acc[2][4];
    #pragma unroll
    for (int mi = 0; mi < 2; mi++)
        #pragma unroll
        for (int ni = 0; ni < 4; ni++)
            acc[mi][ni] = (f32x4){0.f, 0.f, 0.f, 0.f};

    #pragma unroll
    for (int ks = 0; ks < 8; ks++) {
        bf16x8 a[2];
        #pragma unroll
        for (int mi = 0; mi < 2; mi++)
            a[mi] = *(const bf16x8*)(sY + (mi * 16 + col) * 264 + ks * 32 + quad * 8);
        #pragma unroll
        for (int mi = 0; mi < 2; mi++)
            #pragma unroll
            for (int ni = 0; ni < 4; ni++)
                acc[mi][ni] = MFMA(a[mi], wf[ni][ks], acc[mi][ni]);
    }

    float* ob = out + (size_t)(b * S + s0) * D;
    #pragma unroll
    for (int ni = 0; ni < 4; ni++) {
        int d = w * 64 + ni * 16 + col;
        float bvv = bv[d];
        #pragma unroll
        for (int mi = 0; mi < 2; mi++)
            #pragma unroll
            for (int r = 0; r < 4; r++)
                ob[(size_t)(mi * 16 + quad * 4 + r) * D + d] = acc[mi][ni][r] + bvv;
    }
}

extern "C" void kernel_launch(void* const* d_in, const int* in_sizes, int n_in,
                              void* d_out, int out_size, void* d_ws, size_t ws_size,
                              hipStream_t stream) {
    const float* x    = (const float*)d_in[0];
    const float* Wv   = (const float*)d_in[1];
    const float* bv   = (const float*)d_in[2];
    const float* logt = (const float*)d_in[3];
    float* out = (float*)d_out;

    char* ws = (char*)d_ws;
    unsigned char* xb8 = (unsigned char*)ws;          // fp8 x (swizzled) [B][S][D]   4 MB
    short* xt  = (short*)(ws + 4194304);              // bf16 x^T [B][D][S]           8 MB
    short* wb  = (short*)(ws + 12582912);             // bf16 W [D][D]                128 KB
    float* sq  = (float*)(ws + 12713984);             // ||x||^2 [B][S]               64 KB
    float* rws = (float*)(ws + 12779520);             // rowsums [2][B][S]            128 KB
    _Float16* pex = (_Float16*)(ws + 12910592);       // fp16 Y partials [2][B][S][D] 16.78 MB

    k_prep<<<264, 512, 0, stream>>>(x, Wv, xb8, xt, wb, sq);
    k_attn<2><<<NB * (S / 64) * 2, 256, 0, stream>>>(xb8, xt, sq, logt, pex, rws);
    k_post<<<NB * (S / 32), 256, 0, stream>>>(pex, rws, wb, bv, out);
}